// Round 3
// baseline (667.089 us; speedup 1.0000x reference)
//
#include <hip/hip_runtime.h>
#include <math.h>

// N=16384 rows, C=1000 cols, 7 heads. Row stride 4000 B -> 16B aligned.
// 250 float4/row = 3*64 + 58: iters 0..2 unconditional, iter 3 guarded.
//
// Persistent-wave design: NW = N/4 waves (4096), grid = N/16 blocks (1024,
// fully resident at 4 blocks/CU with <=128 VGPR). Wave w owns row-pairs
// p0 = w and p1 = w + NW (rows 2p, 2p+1), iterates h = 0..6 over heads,
// software-pipelined: next task's loads (8x float4 + 2 target gathers)
// issued before reducing the current task -> loads always in flight,
// no dependent gather in the wave tail, no barriers, no block churn.

#define WAVES_PER_BLOCK 4

struct Task {
    float4 a0, a1, a2, a3;   // row r
    float4 c0, c1, c2, c3;   // row r+1
    float tv0, tv1;          // x[target] for each row
};

__device__ __forceinline__ void issue_task(Task& t, const float* __restrict__ base,
                                           int r, int C, int lane, int t0, int t1) {
    const float* b0 = base + (size_t)r * C;
    const float* b1 = b0 + C;
    const float4* v0 = (const float4*)b0;
    const float4* v1 = (const float4*)b1;
    const int nvec = C >> 2;
    t.a0 = v0[lane];       t.c0 = v1[lane];
    t.a1 = v0[64 + lane];  t.c1 = v1[64 + lane];
    t.a2 = v0[128 + lane]; t.c2 = v1[128 + lane];
    if (192 + lane < nvec) { t.a3 = v0[192 + lane]; t.c3 = v1[192 + lane]; }
    else {
        t.a3 = make_float4(-INFINITY, -INFINITY, -INFINITY, -INFINITY);
        t.c3 = t.a3;
    }
    t.tv0 = b0[t0];        // uniform address -> broadcast, issued with row loads
    t.tv1 = b1[t1];
}

__device__ __forceinline__ void reduce_task(const Task& t,
                                            float& m1a, float& m2a,
                                            float& m1c, float& m2c) {
    float va[16] = {t.a0.x,t.a0.y,t.a0.z,t.a0.w, t.a1.x,t.a1.y,t.a1.z,t.a1.w,
                    t.a2.x,t.a2.y,t.a2.z,t.a2.w, t.a3.x,t.a3.y,t.a3.z,t.a3.w};
    float vc[16] = {t.c0.x,t.c0.y,t.c0.z,t.c0.w, t.c1.x,t.c1.y,t.c1.z,t.c1.w,
                    t.c2.x,t.c2.y,t.c2.z,t.c2.w, t.c3.x,t.c3.y,t.c3.z,t.c3.w};
    m1a = -INFINITY; m2a = -INFINITY; m1c = -INFINITY; m2c = -INFINITY;
    #pragma unroll
    for (int k = 0; k < 16; ++k) {
        float x = va[k];
        m2a = fmaxf(m2a, fminf(m1a, x));
        m1a = fmaxf(m1a, x);
        float y = vc[k];
        m2c = fmaxf(m2c, fminf(m1c, y));
        m1c = fmaxf(m1c, y);
    }
    #pragma unroll
    for (int off = 32; off >= 1; off >>= 1) {
        float o1a = __shfl_xor(m1a, off);
        float o2a = __shfl_xor(m2a, off);
        float o1c = __shfl_xor(m1c, off);
        float o2c = __shfl_xor(m2c, off);
        m2a = fmaxf(fmaxf(m2a, o2a), fminf(m1a, o1a));
        m1a = fmaxf(m1a, o1a);
        m2c = fmaxf(fmaxf(m2c, o2c), fminf(m1c, o1c));
        m1c = fmaxf(m1c, o1c);
    }
}

__global__ __launch_bounds__(256, 4) void margin_kernel(
    const float* __restrict__ h0, const float* __restrict__ h1,
    const float* __restrict__ h2, const float* __restrict__ h3,
    const float* __restrict__ h4, const float* __restrict__ h5,
    const float* __restrict__ h6,
    const int* __restrict__ targets,
    float* __restrict__ margins,   // [7*N]  margins[head*N + row]
    float* __restrict__ partials,  // [N/4]  per-wave max over heads 0..5
    int N, int C)
{
    const int lane = threadIdx.x & 63;
    const int waveInBlock = threadIdx.x >> 6;
    const int w = blockIdx.x * WAVES_PER_BLOCK + waveInBlock;  // [0, N/4)
    const int NW = N >> 2;

    const float* const hp[7] = {h0, h1, h2, h3, h4, h5, h6};

    const int rA = 2 * w;            // pair 0 rows: rA, rA+1
    const int rB = 2 * w + (N >> 1); // pair 1 rows: rB, rB+1
    const int tA0 = targets[rA],     tA1 = targets[rA + 1];
    const int tB0 = targets[rB],     tB1 = targets[rB + 1];

    Task cur, nxt;
    issue_task(cur, hp[0], rA, C, lane, tA0, tA1);

    float wmax = -INFINITY;
    float m1a, m2a, m1c, m2c;

    #pragma unroll
    for (int it = 0; it < 14; ++it) {
        const int h = it >> 1;
        const int s = it & 1;                  // 0 -> pair A, 1 -> pair B
        if (it < 13) {
            const int itn = it + 1;
            const int hn = itn >> 1, sn = itn & 1;
            issue_task(nxt, hp[hn], sn ? rB : rA, C, lane,
                       sn ? tB0 : tA0, sn ? tB1 : tA1);
        }
        reduce_task(cur, m1a, m2a, m1c, m2c);
        const int r = s ? rB : rA;
        if (lane == 0) {
            margins[h * N + r]     = (cur.tv0 == m1a) ? (m1a - m2a) : 0.0f;
            margins[h * N + r + 1] = (cur.tv1 == m1c) ? (m1c - m2c) : 0.0f;
        }
        if (h < 6) wmax = fmaxf(wmax, fmaxf(m1a, m1c));
        cur = nxt;
    }
    if (lane == 0) partials[w] = wmax;
}

// Block 0: reduce partials -> out[0].  Blocks 1..: per-row 7-way softmax.
__global__ __launch_bounds__(256) void epilogue_kernel(
    const float* __restrict__ margins, const float* __restrict__ partials,
    int npart, float* __restrict__ out, int N)
{
    if (blockIdx.x == 0) {
        float m = -INFINITY;
        for (int i = threadIdx.x; i < npart; i += 256) m = fmaxf(m, partials[i]);
        #pragma unroll
        for (int off = 32; off >= 1; off >>= 1) m = fmaxf(m, __shfl_xor(m, off));
        __shared__ float s[4];
        int lane = threadIdx.x & 63, wv = threadIdx.x >> 6;
        if (lane == 0) s[wv] = m;
        __syncthreads();
        if (threadIdx.x == 0)
            out[0] = fmaxf(fmaxf(s[0], s[1]), fmaxf(s[2], s[3]));
        return;
    }
    int row = (blockIdx.x - 1) * 256 + threadIdx.x;
    if (row >= N) return;
    float m[7];
    float mx = -INFINITY;
    #pragma unroll
    for (int j = 0; j < 7; ++j) { m[j] = margins[j * N + row]; mx = fmaxf(mx, m[j]); }
    float s = 0.0f;
    #pragma unroll
    for (int j = 0; j < 7; ++j) { m[j] = expf((m[j] - mx) * 0.5f); s += m[j]; }
    float inv = 1.0f / s;
    float* o = out + 1 + (size_t)row * 7;
    #pragma unroll
    for (int j = 0; j < 7; ++j) o[j] = m[j] * inv;
}

extern "C" void kernel_launch(void* const* d_in, const int* in_sizes, int n_in,
                              void* d_out, int out_size, void* d_ws, size_t ws_size,
                              hipStream_t stream) {
    const float* h0 = (const float*)d_in[0];
    const float* h1 = (const float*)d_in[1];
    const float* h2 = (const float*)d_in[2];
    const float* h3 = (const float*)d_in[3];
    const float* h4 = (const float*)d_in[4];
    const float* h5 = (const float*)d_in[5];
    const float* h6 = (const float*)d_in[6];  // mimic
    const int* targets = (const int*)d_in[7];

    const int N = in_sizes[7];          // 16384
    const int C = in_sizes[0] / N;      // 1000

    float* margins  = (float*)d_ws;               // 7*N floats
    float* partials = margins + 7 * N;            // N/4 floats

    const int NW = N / 4;                         // 4096 waves
    const int nblocks = NW / WAVES_PER_BLOCK;     // 1024 blocks

    margin_kernel<<<nblocks, 256, 0, stream>>>(h0, h1, h2, h3, h4, h5, h6,
                                               targets, margins, partials, N, C);
    epilogue_kernel<<<1 + (N + 255) / 256, 256, 0, stream>>>(margins, partials,
                                                             NW, (float*)d_out, N);
}

// Round 4
// 390.148 us; speedup vs baseline: 1.7098x; 1.7098x over previous
//
#include <hip/hip_runtime.h>
#include <math.h>

// N=16384 rows, C=1000 cols, 7 heads. Row stride 4000 B -> 16B aligned, float4 ok.
// 250 float4 per row = 3*64 + 58 -> iters 0..2 unconditional, iter 3 padded with -INF.
// Each wave handles 2 rows (8 independent float4 loads in flight).
// grid.y = head (0..6)  -> no integer division, block-uniform pointer pick.
//
// R3 lesson: do NOT pipeline with big per-wave structs / dynamic pointer arrays —
// the compiler spills them to scratch (924 MB of scratch traffic, 3x regression).
// This structure reads at ~3.4 TB/s app-level, which matches the chip's measured
// read-stream ceiling (~5.5 B/cyc/CU outstanding-limit; m13 copy = 3.15 TB/s/dir).

#define WAVES_PER_BLOCK 4
#define ROWS_PER_WAVE 2
#define ROWS_PER_BLOCK (WAVES_PER_BLOCK * ROWS_PER_WAVE)   // 8

__global__ __launch_bounds__(256) void margin_kernel(
    const float* __restrict__ h0, const float* __restrict__ h1,
    const float* __restrict__ h2, const float* __restrict__ h3,
    const float* __restrict__ h4, const float* __restrict__ h5,
    const float* __restrict__ h6,
    const int* __restrict__ targets,
    float* __restrict__ margins,   // [7*N]  margins[head*N + row]
    float* __restrict__ partials,  // [6 * (N/ROWS_PER_BLOCK)] block maxima, heads 0..5 only
    int N, int C)
{
    const int lane = threadIdx.x & 63;
    const int waveInBlock = threadIdx.x >> 6;
    const int head = blockIdx.y;

    const float* base;
    switch (head) {
        case 0: base = h0; break;
        case 1: base = h1; break;
        case 2: base = h2; break;
        case 3: base = h3; break;
        case 4: base = h4; break;
        case 5: base = h5; break;
        default: base = h6; break;
    }

    const int row0 = (blockIdx.x * WAVES_PER_BLOCK + waveInBlock) * ROWS_PER_WAVE;
    const int row1 = row0 + 1;
    const float* b0 = base + (size_t)row0 * C;
    const float* b1 = base + (size_t)row1 * C;
    const float4* v0 = (const float4*)b0;
    const float4* v1 = (const float4*)b1;
    const int nvec = C >> 2;   // 250

    // Issue all 8 loads up front; tail iter padded with -INF.
    float4 a0 = v0[lane];
    float4 a1 = v0[64 + lane];
    float4 a2 = v0[128 + lane];
    float4 c0 = v1[lane];
    float4 c1 = v1[64 + lane];
    float4 c2 = v1[128 + lane];
    float4 a3 = make_float4(-INFINITY, -INFINITY, -INFINITY, -INFINITY);
    float4 c3 = a3;
    if (192 + lane < nvec) {
        a3 = v0[192 + lane];
        c3 = v1[192 + lane];
    }

    // Branchless top-2: depth-2 chain, two independent chains (row0, row1).
    float m1a = -INFINITY, m2a = -INFINITY;
    float m1c = -INFINITY, m2c = -INFINITY;
    float va[16] = {a0.x,a0.y,a0.z,a0.w, a1.x,a1.y,a1.z,a1.w,
                    a2.x,a2.y,a2.z,a2.w, a3.x,a3.y,a3.z,a3.w};
    float vc[16] = {c0.x,c0.y,c0.z,c0.w, c1.x,c1.y,c1.z,c1.w,
                    c2.x,c2.y,c2.z,c2.w, c3.x,c3.y,c3.z,c3.w};
    #pragma unroll
    for (int k = 0; k < 16; ++k) {
        float x = va[k];
        m2a = fmaxf(m2a, fminf(m1a, x));
        m1a = fmaxf(m1a, x);
        float y = vc[k];
        m2c = fmaxf(m2c, fminf(m1c, y));
        m1c = fmaxf(m1c, y);
    }

    // 64-lane butterfly top-2 reduction, both rows interleaved.
    #pragma unroll
    for (int off = 32; off >= 1; off >>= 1) {
        float o1a = __shfl_xor(m1a, off);
        float o2a = __shfl_xor(m2a, off);
        float o1c = __shfl_xor(m1c, off);
        float o2c = __shfl_xor(m2c, off);
        m2a = fmaxf(fmaxf(m2a, o2a), fminf(m1a, o1a));
        m1a = fmaxf(m1a, o1a);
        m2c = fmaxf(fmaxf(m2c, o2c), fminf(m1c, o1c));
        m1c = fmaxf(m1c, o1c);
    }

    __shared__ float smax[WAVES_PER_BLOCK];
    if (lane == 0) {
        int t0 = targets[row0];
        int t1 = targets[row1];
        float tv0 = b0[t0];
        float tv1 = b1[t1];
        margins[head * N + row0] = (tv0 == m1a) ? (m1a - m2a) : 0.0f;
        margins[head * N + row1] = (tv1 == m1c) ? (m1c - m2c) : 0.0f;
        smax[waveInBlock] = fmaxf(m1a, m1c);
    }
    __syncthreads();
    if (threadIdx.x == 0 && head < 6) {
        float bm = fmaxf(fmaxf(smax[0], smax[1]), fmaxf(smax[2], smax[3]));
        partials[head * gridDim.x + blockIdx.x] = bm;
    }
}

// Block 0: reduce partials -> out[0].  Blocks 1..: per-row 7-way softmax -> out[1..].
__global__ __launch_bounds__(256) void epilogue_kernel(
    const float* __restrict__ margins, const float* __restrict__ partials,
    int npart, float* __restrict__ out, int N)
{
    if (blockIdx.x == 0) {
        float m = -INFINITY;
        for (int i = threadIdx.x; i < npart; i += 256) m = fmaxf(m, partials[i]);
        #pragma unroll
        for (int off = 32; off >= 1; off >>= 1) m = fmaxf(m, __shfl_xor(m, off));
        __shared__ float s[4];
        int lane = threadIdx.x & 63, w = threadIdx.x >> 6;
        if (lane == 0) s[w] = m;
        __syncthreads();
        if (threadIdx.x == 0)
            out[0] = fmaxf(fmaxf(s[0], s[1]), fmaxf(s[2], s[3]));
        return;
    }
    int row = (blockIdx.x - 1) * 256 + threadIdx.x;
    if (row >= N) return;
    float m[7];
    float mx = -INFINITY;
    #pragma unroll
    for (int j = 0; j < 7; ++j) { m[j] = margins[j * N + row]; mx = fmaxf(mx, m[j]); }
    float s = 0.0f;
    #pragma unroll
    for (int j = 0; j < 7; ++j) { m[j] = expf((m[j] - mx) * 0.5f); s += m[j]; }
    float inv = 1.0f / s;
    float* o = out + 1 + (size_t)row * 7;
    #pragma unroll
    for (int j = 0; j < 7; ++j) o[j] = m[j] * inv;
}

extern "C" void kernel_launch(void* const* d_in, const int* in_sizes, int n_in,
                              void* d_out, int out_size, void* d_ws, size_t ws_size,
                              hipStream_t stream) {
    const float* h0 = (const float*)d_in[0];
    const float* h1 = (const float*)d_in[1];
    const float* h2 = (const float*)d_in[2];
    const float* h3 = (const float*)d_in[3];
    const float* h4 = (const float*)d_in[4];
    const float* h5 = (const float*)d_in[5];
    const float* h6 = (const float*)d_in[6];  // mimic
    const int* targets = (const int*)d_in[7];

    const int N = in_sizes[7];          // 16384
    const int C = in_sizes[0] / N;      // 1000

    float* margins  = (float*)d_ws;               // 7*N floats
    float* partials = margins + 7 * N;            // 6 * (N/8) floats

    const int blocksX = N / ROWS_PER_BLOCK;       // 2048
    const int npart = 6 * blocksX;

    dim3 grid(blocksX, 7, 1);
    margin_kernel<<<grid, 256, 0, stream>>>(h0, h1, h2, h3, h4, h5, h6,
                                            targets, margins, partials, N, C);
    epilogue_kernel<<<1 + (N + 255) / 256, 256, 0, stream>>>(margins, partials,
                                                             npart, (float*)d_out, N);
}